// Round 1
// baseline (1309.981 us; speedup 1.0000x reference)
//
#include <hip/hip_runtime.h>
#include <math.h>

#define EMB  768
#define NH   12
#define HD   64
#define SEQ  2048
#define BATCH 2
#define BM 64
#define BN 64
#define BK 64

// ---------------------------------------------------------------------------
// Kernel 1: fused QKV projection.  C[4096, 2304] = X[4096,768] @ W^T + b,
// where the 2304 output columns are [Wq | Wk | Wv] (each [768,768] row-major,
// i.e. torch Linear weight: out_j = sum_i x_i * W[j][i]).
// Stores q/k/v in [b, h, n, d] layout; q is scaled by 1/8 after bias.
// ---------------------------------------------------------------------------
__global__ __launch_bounds__(256) void qkv_kernel(
    const float* __restrict__ x,
    const float* __restrict__ wq, const float* __restrict__ bq,
    const float* __restrict__ wk, const float* __restrict__ bk,
    const float* __restrict__ wv, const float* __restrict__ bv,
    float* __restrict__ q, float* __restrict__ k, float* __restrict__ v)
{
    __shared__ float As[BM][BK + 1];
    __shared__ float Bs[BN][BK + 1];
    const int tid = threadIdx.x;
    const int tx = tid & 15, ty = tid >> 4;
    const int m0 = blockIdx.y * BM;          // token tile
    const int j0 = blockIdx.x * BN;          // global output col in [0,2304)
    const int mat = j0 / EMB;                // 0=q 1=k 2=v (tiles never straddle)
    const int jj0 = j0 - mat * EMB;
    const float* W  = (mat == 0) ? wq : (mat == 1) ? wk : wv;
    const float* Bb = (mat == 0) ? bq : (mat == 1) ? bk : bv;
    float* dst      = (mat == 0) ? q  : (mat == 1) ? k  : v;

    float acc[4][4] = {};
    for (int kb = 0; kb < EMB; kb += BK) {
        #pragma unroll
        for (int l = 0; l < 16; ++l) {
            int idx = l * 256 + tid;
            int r = idx >> 6, c = idx & 63;
            As[r][c] = x[(size_t)(m0 + r) * EMB + kb + c];
            Bs[r][c] = W[(size_t)(jj0 + r) * EMB + kb + c];
        }
        __syncthreads();
        #pragma unroll 8
        for (int kk = 0; kk < BK; ++kk) {
            float a[4], b[4];
            #pragma unroll
            for (int i = 0; i < 4; ++i) a[i] = As[ty * 4 + i][kk];
            #pragma unroll
            for (int j = 0; j < 4; ++j) b[j] = Bs[tx * 4 + j][kk];
            #pragma unroll
            for (int i = 0; i < 4; ++i)
                #pragma unroll
                for (int j = 0; j < 4; ++j)
                    acc[i][j] = fmaf(a[i], b[j], acc[i][j]);
        }
        __syncthreads();
    }
    const float scale = (mat == 0) ? 0.125f : 1.0f;
    #pragma unroll
    for (int i = 0; i < 4; ++i) {
        int gm = m0 + ty * 4 + i;            // global token in [0,4096)
        int bidx = gm >> 11;                 // batch
        int n = gm & (SEQ - 1);
        #pragma unroll
        for (int j = 0; j < 4; ++j) {
            int gj = jj0 + tx * 4 + j;       // col within this matrix [0,768)
            int h = gj >> 6, d = gj & 63;
            float val = (acc[i][j] + Bb[gj]) * scale;
            dst[(((size_t)bidx * NH + h) * SEQ + n) * HD + d] = val;
        }
    }
}

// ---------------------------------------------------------------------------
// Kernel 2: flash-style causal attention.  One block per (q-tile of 64 rows,
// batch*head).  Online softmax; O accumulated in registers; S tile in LDS.
// q/k/v layout: [b, h, n, d].  Output written to [b, n, emb] layout.
// ---------------------------------------------------------------------------
__global__ __launch_bounds__(256) void attn_kernel(
    const float* __restrict__ q, const float* __restrict__ k,
    const float* __restrict__ v, float* __restrict__ o)
{
    __shared__ float Qs[64][HD + 1];
    __shared__ float Ks[64][HD + 1];
    __shared__ float Vs[64][HD + 1];
    __shared__ float Ss[64][64 + 1];
    __shared__ float alpha_s[64];
    __shared__ float l_s[64];

    const int tid = threadIdx.x;
    const int tx = tid & 15, ty = tid >> 4;
    const int qt = blockIdx.x;               // 0..31
    const int bh = blockIdx.y;               // 0..23  (= b*NH + h)
    const size_t base = (size_t)bh * SEQ * HD;
    const int q0 = qt * 64;

    #pragma unroll
    for (int l = 0; l < 16; ++l) {
        int idx = l * 256 + tid;
        int r = idx >> 6, c = idx & 63;
        Qs[r][c] = q[base + (size_t)(q0 + r) * HD + c];
    }
    float m_i = -1e30f, l_i = 0.f;           // live only in threads tid<64 (row=tid)
    float accO[4][4] = {};
    __syncthreads();

    for (int kt = 0; kt <= qt; ++kt) {
        const int k0 = kt * 64;
        #pragma unroll
        for (int l = 0; l < 16; ++l) {
            int idx = l * 256 + tid;
            int r = idx >> 6, c = idx & 63;
            Ks[r][c] = k[base + (size_t)(k0 + r) * HD + c];
            Vs[r][c] = v[base + (size_t)(k0 + r) * HD + c];
        }
        __syncthreads();

        // S = Q @ K^T  (4x4 micro-tile per thread)
        float sacc[4][4] = {};
        #pragma unroll 8
        for (int kk = 0; kk < HD; ++kk) {
            float a[4], b[4];
            #pragma unroll
            for (int i = 0; i < 4; ++i) a[i] = Qs[ty * 4 + i][kk];
            #pragma unroll
            for (int j = 0; j < 4; ++j) b[j] = Ks[tx * 4 + j][kk];
            #pragma unroll
            for (int i = 0; i < 4; ++i)
                #pragma unroll
                for (int j = 0; j < 4; ++j)
                    sacc[i][j] = fmaf(a[i], b[j], sacc[i][j]);
        }
        if (kt == qt) {                      // causal mask on diagonal tile
            #pragma unroll
            for (int i = 0; i < 4; ++i)
                #pragma unroll
                for (int j = 0; j < 4; ++j)
                    if (tx * 4 + j > ty * 4 + i) sacc[i][j] = -1e30f;
        }
        #pragma unroll
        for (int i = 0; i < 4; ++i)
            #pragma unroll
            for (int j = 0; j < 4; ++j)
                Ss[ty * 4 + i][tx * 4 + j] = sacc[i][j];
        __syncthreads();

        // online softmax per row (row i handled by thread i)
        if (tid < 64) {
            float mnew = m_i;
            #pragma unroll 8
            for (int j = 0; j < 64; ++j) mnew = fmaxf(mnew, Ss[tid][j]);
            float al = expf(m_i - mnew);
            float lsum = 0.f;
            #pragma unroll 8
            for (int j = 0; j < 64; ++j) {
                float p = expf(Ss[tid][j] - mnew);
                Ss[tid][j] = p;
                lsum += p;
            }
            l_i = l_i * al + lsum;
            m_i = mnew;
            alpha_s[tid] = al;
            l_s[tid] = l_i;
        }
        __syncthreads();

        // O = O*alpha + P @ V
        float a_r[4];
        #pragma unroll
        for (int i = 0; i < 4; ++i) a_r[i] = alpha_s[ty * 4 + i];
        #pragma unroll
        for (int i = 0; i < 4; ++i)
            #pragma unroll
            for (int j = 0; j < 4; ++j) accO[i][j] *= a_r[i];
        #pragma unroll 8
        for (int kk = 0; kk < 64; ++kk) {
            float p[4], vv[4];
            #pragma unroll
            for (int i = 0; i < 4; ++i) p[i] = Ss[ty * 4 + i][kk];
            #pragma unroll
            for (int j = 0; j < 4; ++j) vv[j] = Vs[kk][tx * 4 + j];
            #pragma unroll
            for (int i = 0; i < 4; ++i)
                #pragma unroll
                for (int j = 0; j < 4; ++j)
                    accO[i][j] = fmaf(p[i], vv[j], accO[i][j]);
        }
        __syncthreads();                     // before next K/V overwrite
    }

    // epilogue: divide by l, write to [b, n, emb]
    const int b = bh / NH, h = bh % NH;
    #pragma unroll
    for (int i = 0; i < 4; ++i) {
        int r = ty * 4 + i;
        float inv_l = 1.0f / l_s[r];
        int n = q0 + r;
        #pragma unroll
        for (int j = 0; j < 4; ++j) {
            int d = tx * 4 + j;
            o[((size_t)b * SEQ + n) * EMB + h * HD + d] = accO[i][j] * inv_l;
        }
    }
}

// ---------------------------------------------------------------------------
// Kernel 3: output projection.  C[4096,768] = A[4096,768] @ Wo^T + bo.
// ---------------------------------------------------------------------------
__global__ __launch_bounds__(256) void out_proj_kernel(
    const float* __restrict__ a, const float* __restrict__ w,
    const float* __restrict__ bias, float* __restrict__ c)
{
    __shared__ float As[BM][BK + 1];
    __shared__ float Bs[BN][BK + 1];
    const int tid = threadIdx.x;
    const int tx = tid & 15, ty = tid >> 4;
    const int m0 = blockIdx.y * BM;
    const int j0 = blockIdx.x * BN;

    float acc[4][4] = {};
    for (int kb = 0; kb < EMB; kb += BK) {
        #pragma unroll
        for (int l = 0; l < 16; ++l) {
            int idx = l * 256 + tid;
            int r = idx >> 6, cc = idx & 63;
            As[r][cc] = a[(size_t)(m0 + r) * EMB + kb + cc];
            Bs[r][cc] = w[(size_t)(j0 + r) * EMB + kb + cc];
        }
        __syncthreads();
        #pragma unroll 8
        for (int kk = 0; kk < BK; ++kk) {
            float av[4], bv[4];
            #pragma unroll
            for (int i = 0; i < 4; ++i) av[i] = As[ty * 4 + i][kk];
            #pragma unroll
            for (int j = 0; j < 4; ++j) bv[j] = Bs[tx * 4 + j][kk];
            #pragma unroll
            for (int i = 0; i < 4; ++i)
                #pragma unroll
                for (int j = 0; j < 4; ++j)
                    acc[i][j] = fmaf(av[i], bv[j], acc[i][j]);
        }
        __syncthreads();
    }
    #pragma unroll
    for (int i = 0; i < 4; ++i) {
        int gm = m0 + ty * 4 + i;
        #pragma unroll
        for (int j = 0; j < 4; ++j) {
            int gj = j0 + tx * 4 + j;
            c[(size_t)gm * EMB + gj] = acc[i][j] + bias[gj];
        }
    }
}

extern "C" void kernel_launch(void* const* d_in, const int* in_sizes, int n_in,
                              void* d_out, int out_size, void* d_ws, size_t ws_size,
                              hipStream_t stream) {
    const float* x  = (const float*)d_in[0];
    const float* wq = (const float*)d_in[1];
    const float* bq = (const float*)d_in[2];
    const float* wk = (const float*)d_in[3];
    const float* bk = (const float*)d_in[4];
    const float* wv = (const float*)d_in[5];
    const float* bv = (const float*)d_in[6];
    const float* wo = (const float*)d_in[7];
    const float* bo = (const float*)d_in[8];
    float* out = (float*)d_out;

    const size_t tok_elems = (size_t)BATCH * SEQ * EMB;  // 3,145,728
    float* q  = (float*)d_ws;
    float* k  = q + tok_elems;
    float* v  = k + tok_elems;
    float* ao = v + tok_elems;   // attention output, [b, n, emb]

    // QKV projection: M=4096 tokens (64 tiles), N=2304 cols (36 tiles)
    qkv_kernel<<<dim3(36, 64), 256, 0, stream>>>(x, wq, bq, wk, bk, wv, bv, q, k, v);
    // Attention: 32 q-tiles x 24 (b*h)
    attn_kernel<<<dim3(32, 24), 256, 0, stream>>>(q, k, v, ao);
    // Output projection: N=768 (12 tiles), M=4096 (64 tiles)
    out_proj_kernel<<<dim3(12, 64), 256, 0, stream>>>(ao, wo, bo, out);
}

// Round 2
// 218.313 us; speedup vs baseline: 6.0005x; 6.0005x over previous
//
#include <hip/hip_runtime.h>
#include <hip/hip_bf16.h>
#include <math.h>

#define EMB  768
#define NH   12
#define HD   64
#define SEQ  2048
#define BATCH 2
#define NTOK 4096           // BATCH*SEQ

typedef __attribute__((ext_vector_type(8))) short short8;   // 8 bf16 = 4 VGPRs
typedef __attribute__((ext_vector_type(4))) float float4v;  // 4 fp32 acc

static __device__ inline short f2bf(float f) {
    __hip_bfloat16 h = __float2bfloat16(f);
    return *reinterpret_cast<short*>(&h);
}

// ---------------------------------------------------------------------------
// Kernel 0: cast x + 4 weights fp32 -> bf16 into workspace.
// ---------------------------------------------------------------------------
__global__ __launch_bounds__(256) void cast_kernel(
    const float* __restrict__ x,  const float* __restrict__ wq,
    const float* __restrict__ wk, const float* __restrict__ wv,
    const float* __restrict__ wo,
    __hip_bfloat16* __restrict__ xb,  __hip_bfloat16* __restrict__ wqb,
    __hip_bfloat16* __restrict__ wkb, __hip_bfloat16* __restrict__ wvb,
    __hip_bfloat16* __restrict__ wob)
{
    const size_t S0 = (size_t)NTOK * EMB;       // 3,145,728
    const size_t S1 = (size_t)EMB * EMB;        //   589,824
    size_t i = ((size_t)blockIdx.x * 256 + threadIdx.x) * 8;
    const float* src; __hip_bfloat16* dst; size_t off;
    if      (i < S0)            { src = x;  dst = xb;  off = i; }
    else if (i < S0 + S1)       { src = wq; dst = wqb; off = i - S0; }
    else if (i < S0 + 2 * S1)   { src = wk; dst = wkb; off = i - S0 - S1; }
    else if (i < S0 + 3 * S1)   { src = wv; dst = wvb; off = i - S0 - 2 * S1; }
    else                        { src = wo; dst = wob; off = i - S0 - 3 * S1; }
    float4 f0 = *(const float4*)&src[off];
    float4 f1 = *(const float4*)&src[off + 4];
    short8 o;
    o[0] = f2bf(f0.x); o[1] = f2bf(f0.y); o[2] = f2bf(f0.z); o[3] = f2bf(f0.w);
    o[4] = f2bf(f1.x); o[5] = f2bf(f1.y); o[6] = f2bf(f1.z); o[7] = f2bf(f1.w);
    *(short8*)&dst[off] = o;
}

// ---------------------------------------------------------------------------
// Kernel 1: fused QKV projection, bf16 MFMA.
// C[4096, 2304] = Xb @ [Wq|Wk|Wv]^T + bias; q scaled 1/8; out [b,h,n,d] bf16.
// 128x128 tile, 4 waves each 64x64 (4x4 MFMA tiles), BK=64.
// ---------------------------------------------------------------------------
__global__ __launch_bounds__(256) void qkv_mfma_kernel(
    const __hip_bfloat16* __restrict__ xb,
    const __hip_bfloat16* __restrict__ wqb, const float* __restrict__ bq,
    const __hip_bfloat16* __restrict__ wkb, const float* __restrict__ bk,
    const __hip_bfloat16* __restrict__ wvb, const float* __restrict__ bv,
    __hip_bfloat16* __restrict__ q, __hip_bfloat16* __restrict__ k,
    __hip_bfloat16* __restrict__ v)
{
    __shared__ short As[128][72];   // stride 144 B = 36 words -> b128 conflict-free
    __shared__ short Bs[128][72];
    const int t = threadIdx.x;
    const int w = t >> 6, lane = t & 63;
    const int col = lane & 15, quad = lane >> 4;
    const int wm = w >> 1, wn = w & 1;
    const int m0 = blockIdx.y * 128;
    const int mat = blockIdx.x / 6;             // 0=q 1=k 2=v (6 n-tiles per matrix)
    const int jj0 = (blockIdx.x % 6) * 128;     // col offset within this W
    const __hip_bfloat16* W = (mat == 0) ? wqb : (mat == 1) ? wkb : wvb;
    const float* bias        = (mat == 0) ? bq  : (mat == 1) ? bk  : bv;
    __hip_bfloat16* dst      = (mat == 0) ? q   : (mat == 1) ? k   : v;
    const float scale = (mat == 0) ? 0.125f : 1.0f;

    float4v acc[4][4];
    #pragma unroll
    for (int mi = 0; mi < 4; ++mi)
        #pragma unroll
        for (int ni = 0; ni < 4; ++ni) acc[mi][ni] = (float4v){0.f, 0.f, 0.f, 0.f};

    for (int kb = 0; kb < EMB; kb += 64) {
        #pragma unroll
        for (int c = 0; c < 4; ++c) {
            int id = c * 256 + t;               // 0..1023
            int row = id >> 3, c8 = id & 7;
            *(uint4*)&As[row][c8 * 8] =
                *(const uint4*)&xb[(size_t)(m0 + row) * EMB + kb + c8 * 8];
            *(uint4*)&Bs[row][c8 * 8] =
                *(const uint4*)&W[(size_t)(jj0 + row) * EMB + kb + c8 * 8];
        }
        __syncthreads();
        #pragma unroll
        for (int ks = 0; ks < 2; ++ks) {
            short8 a[4], b[4];
            #pragma unroll
            for (int mi = 0; mi < 4; ++mi)
                a[mi] = *(short8*)&As[wm * 64 + mi * 16 + col][ks * 32 + quad * 8];
            #pragma unroll
            for (int ni = 0; ni < 4; ++ni)
                b[ni] = *(short8*)&Bs[wn * 64 + ni * 16 + col][ks * 32 + quad * 8];
            #pragma unroll
            for (int mi = 0; mi < 4; ++mi)
                #pragma unroll
                for (int ni = 0; ni < 4; ++ni)
                    acc[mi][ni] = __builtin_amdgcn_mfma_f32_16x16x32_bf16(
                        a[mi], b[ni], acc[mi][ni], 0, 0, 0);
        }
        __syncthreads();
    }
    #pragma unroll
    for (int mi = 0; mi < 4; ++mi) {
        #pragma unroll
        for (int ni = 0; ni < 4; ++ni) {
            int gj = jj0 + wn * 64 + ni * 16 + col;   // 0..767
            int h = gj >> 6, d = gj & 63;
            float bsv = bias[gj];
            #pragma unroll
            for (int r = 0; r < 4; ++r) {
                int gm = m0 + wm * 64 + mi * 16 + quad * 4 + r;   // token 0..4095
                int bi = gm >> 11, n = gm & (SEQ - 1);
                dst[(((size_t)bi * NH + h) * SEQ + n) * HD + d] =
                    __float2bfloat16((acc[mi][ni][r] + bsv) * scale);
            }
        }
    }
}

// ---------------------------------------------------------------------------
// Kernel 2: transpose V [bh][n][d] -> vT [bh][d][n] (bf16), 64x64 tiles.
// ---------------------------------------------------------------------------
__global__ __launch_bounds__(256) void transpose_v_kernel(
    const __hip_bfloat16* __restrict__ v, __hip_bfloat16* __restrict__ vT)
{
    __shared__ short Ts[64][72];
    const int bh = blockIdx.y;
    const int n0 = blockIdx.x * 64;
    const int t = threadIdx.x;
    #pragma unroll
    for (int c = 0; c < 2; ++c) {
        int id = c * 256 + t;
        int row = id >> 3, c8 = id & 7;
        *(uint4*)&Ts[row][c8 * 8] =
            *(const uint4*)&v[((size_t)bh * SEQ + n0 + row) * HD + c8 * 8];
    }
    __syncthreads();
    #pragma unroll
    for (int c = 0; c < 2; ++c) {
        int id = c * 256 + t;
        int drow = id >> 3, c8 = id & 7;          // drow = d, cols = n
        short8 o;
        #pragma unroll
        for (int j = 0; j < 8; ++j) o[j] = Ts[c8 * 8 + j][drow];
        *(short8*)&vT[((size_t)bh * HD + drow) * SEQ + n0 + c8 * 8] = o;
    }
}

// ---------------------------------------------------------------------------
// Kernel 3: flash causal attention, bf16 MFMA, 64x64 tiles.
// Q frags + online softmax (m,l) + O acc all in registers; P via per-wave LDS.
// Heavy-first block order for causal load balance.
// ---------------------------------------------------------------------------
__global__ __launch_bounds__(256) void attn_mfma_kernel(
    const __hip_bfloat16* __restrict__ q, const __hip_bfloat16* __restrict__ k,
    const __hip_bfloat16* __restrict__ vT, __hip_bfloat16* __restrict__ ao)
{
    __shared__ short Ks[64][72];
    __shared__ short Vt[64][72];
    __shared__ short Ps[4][16][72];
    const int idx = blockIdx.x;
    const int qt = 31 - idx / 24;              // heavy blocks dispatched first
    const int bh = idx % 24;
    const int t = threadIdx.x;
    const int w = t >> 6, lane = t & 63;
    const int col = lane & 15, quad = lane >> 4;
    const int q0 = qt * 64;
    const size_t base = (size_t)bh * SEQ * HD;

    // Q fragments (A-operand): rows q0 + w*16 + col, k = ks*32 + quad*8 .. +7
    short8 qa[2];
    {
        int qrow = q0 + w * 16 + col;
        #pragma unroll
        for (int ks = 0; ks < 2; ++ks)
            qa[ks] = *(const short8*)&q[base + (size_t)qrow * HD + ks * 32 + quad * 8];
    }
    float4v accO[4];
    #pragma unroll
    for (int di = 0; di < 4; ++di) accO[di] = (float4v){0.f, 0.f, 0.f, 0.f};
    float m_i[4], l_i[4];
    #pragma unroll
    for (int r = 0; r < 4; ++r) { m_i[r] = -1e30f; l_i[r] = 0.f; }

    for (int kt = 0; kt <= qt; ++kt) {
        const int k0 = kt * 64;
        #pragma unroll
        for (int c = 0; c < 2; ++c) {
            int id = c * 256 + t;
            int row = id >> 3, c8 = id & 7;
            *(uint4*)&Ks[row][c8 * 8] =
                *(const uint4*)&k[base + (size_t)(k0 + row) * HD + c8 * 8];
            *(uint4*)&Vt[row][c8 * 8] =
                *(const uint4*)&vT[base + (size_t)row * SEQ + k0 + c8 * 8];
        }
        __syncthreads();

        // S = Q @ K^T : 4 n-tiles, 2 k-steps
        float4v s[4];
        #pragma unroll
        for (int ni = 0; ni < 4; ++ni) s[ni] = (float4v){0.f, 0.f, 0.f, 0.f};
        #pragma unroll
        for (int ks = 0; ks < 2; ++ks)
            #pragma unroll
            for (int ni = 0; ni < 4; ++ni) {
                short8 kf = *(short8*)&Ks[ni * 16 + col][ks * 32 + quad * 8];
                s[ni] = __builtin_amdgcn_mfma_f32_16x16x32_bf16(qa[ks], kf, s[ni], 0, 0, 0);
            }
        if (kt == qt) {                        // causal mask on diagonal tile
            #pragma unroll
            for (int ni = 0; ni < 4; ++ni) {
                int gcol = k0 + ni * 16 + col;
                #pragma unroll
                for (int r = 0; r < 4; ++r) {
                    int grow = q0 + w * 16 + quad * 4 + r;
                    if (gcol > grow) s[ni][r] = -1e30f;
                }
            }
        }
        // ---- online softmax, all in registers (rows owned per quad,reg) ----
        float mt[4], lsum[4], alpha[4];
        #pragma unroll
        for (int r = 0; r < 4; ++r)
            mt[r] = fmaxf(fmaxf(s[0][r], s[1][r]), fmaxf(s[2][r], s[3][r]));
        #pragma unroll
        for (int msk = 1; msk < 16; msk <<= 1)
            #pragma unroll
            for (int r = 0; r < 4; ++r)
                mt[r] = fmaxf(mt[r], __shfl_xor(mt[r], msk));
        #pragma unroll
        for (int r = 0; r < 4; ++r) {
            float mn = fmaxf(m_i[r], mt[r]);
            alpha[r] = __expf(m_i[r] - mn);
            m_i[r] = mn;
        }
        #pragma unroll
        for (int ni = 0; ni < 4; ++ni)
            #pragma unroll
            for (int r = 0; r < 4; ++r)
                s[ni][r] = __expf(s[ni][r] - m_i[r]);
        #pragma unroll
        for (int r = 0; r < 4; ++r)
            lsum[r] = (s[0][r] + s[1][r]) + (s[2][r] + s[3][r]);
        #pragma unroll
        for (int msk = 1; msk < 16; msk <<= 1)
            #pragma unroll
            for (int r = 0; r < 4; ++r)
                lsum[r] += __shfl_xor(lsum[r], msk);
        #pragma unroll
        for (int r = 0; r < 4; ++r) l_i[r] = l_i[r] * alpha[r] + lsum[r];
        #pragma unroll
        for (int di = 0; di < 4; ++di)
            #pragma unroll
            for (int r = 0; r < 4; ++r) accO[di][r] *= alpha[r];

        // P (C-layout) -> per-wave LDS -> A-layout frags.  Same-wave RAW: no barrier.
        #pragma unroll
        for (int ni = 0; ni < 4; ++ni)
            #pragma unroll
            for (int r = 0; r < 4; ++r)
                Ps[w][quad * 4 + r][ni * 16 + col] = f2bf(s[ni][r]);
        short8 pa[2];
        #pragma unroll
        for (int ks = 0; ks < 2; ++ks)
            pa[ks] = *(short8*)&Ps[w][col][ks * 32 + quad * 8];

        // O += P @ V  (B-operand from V^T tile)
        #pragma unroll
        for (int ks = 0; ks < 2; ++ks)
            #pragma unroll
            for (int di = 0; di < 4; ++di) {
                short8 vf = *(short8*)&Vt[di * 16 + col][ks * 32 + quad * 8];
                accO[di] = __builtin_amdgcn_mfma_f32_16x16x32_bf16(pa[ks], vf, accO[di], 0, 0, 0);
            }
        __syncthreads();                       // before next K/V staging
    }

    // epilogue: O / l -> ao [b, n, emb] bf16
    const int bi = bh / NH, h = bh % NH;
    #pragma unroll
    for (int r = 0; r < 4; ++r) {
        float inv = 1.0f / l_i[r];
        int n = q0 + w * 16 + quad * 4 + r;
        #pragma unroll
        for (int di = 0; di < 4; ++di)
            ao[((size_t)bi * SEQ + n) * EMB + h * HD + di * 16 + col] =
                __float2bfloat16(accO[di][r] * inv);
    }
}

// ---------------------------------------------------------------------------
// Kernel 4: output projection, bf16 MFMA, fp32 out.
// C[4096,768] = AO @ Wo^T + bo.  128x128 tiles.
// ---------------------------------------------------------------------------
__global__ __launch_bounds__(256) void out_proj_mfma_kernel(
    const __hip_bfloat16* __restrict__ a, const __hip_bfloat16* __restrict__ wob,
    const float* __restrict__ bias, float* __restrict__ out)
{
    __shared__ short As[128][72];
    __shared__ short Bs[128][72];
    const int t = threadIdx.x;
    const int w = t >> 6, lane = t & 63;
    const int col = lane & 15, quad = lane >> 4;
    const int wm = w >> 1, wn = w & 1;
    const int m0 = blockIdx.y * 128;
    const int n0 = blockIdx.x * 128;

    float4v acc[4][4];
    #pragma unroll
    for (int mi = 0; mi < 4; ++mi)
        #pragma unroll
        for (int ni = 0; ni < 4; ++ni) acc[mi][ni] = (float4v){0.f, 0.f, 0.f, 0.f};

    for (int kb = 0; kb < EMB; kb += 64) {
        #pragma unroll
        for (int c = 0; c < 4; ++c) {
            int id = c * 256 + t;
            int row = id >> 3, c8 = id & 7;
            *(uint4*)&As[row][c8 * 8] =
                *(const uint4*)&a[(size_t)(m0 + row) * EMB + kb + c8 * 8];
            *(uint4*)&Bs[row][c8 * 8] =
                *(const uint4*)&wob[(size_t)(n0 + row) * EMB + kb + c8 * 8];
        }
        __syncthreads();
        #pragma unroll
        for (int ks = 0; ks < 2; ++ks) {
            short8 av[4], bv[4];
            #pragma unroll
            for (int mi = 0; mi < 4; ++mi)
                av[mi] = *(short8*)&As[wm * 64 + mi * 16 + col][ks * 32 + quad * 8];
            #pragma unroll
            for (int ni = 0; ni < 4; ++ni)
                bv[ni] = *(short8*)&Bs[wn * 64 + ni * 16 + col][ks * 32 + quad * 8];
            #pragma unroll
            for (int mi = 0; mi < 4; ++mi)
                #pragma unroll
                for (int ni = 0; ni < 4; ++ni)
                    acc[mi][ni] = __builtin_amdgcn_mfma_f32_16x16x32_bf16(
                        av[mi], bv[ni], acc[mi][ni], 0, 0, 0);
        }
        __syncthreads();
    }
    #pragma unroll
    for (int mi = 0; mi < 4; ++mi) {
        #pragma unroll
        for (int ni = 0; ni < 4; ++ni) {
            int gj = n0 + wn * 64 + ni * 16 + col;
            float bsv = bias[gj];
            #pragma unroll
            for (int r = 0; r < 4; ++r) {
                int gm = m0 + wm * 64 + mi * 16 + quad * 4 + r;
                out[(size_t)gm * EMB + gj] = acc[mi][ni][r] + bsv;
            }
        }
    }
}

extern "C" void kernel_launch(void* const* d_in, const int* in_sizes, int n_in,
                              void* d_out, int out_size, void* d_ws, size_t ws_size,
                              hipStream_t stream) {
    const float* x  = (const float*)d_in[0];
    const float* wq = (const float*)d_in[1];
    const float* bq = (const float*)d_in[2];
    const float* wk = (const float*)d_in[3];
    const float* bk = (const float*)d_in[4];
    const float* wv = (const float*)d_in[5];
    const float* bv = (const float*)d_in[6];
    const float* wo = (const float*)d_in[7];
    const float* bo = (const float*)d_in[8];
    float* out = (float*)d_out;

    const size_t TOK = (size_t)NTOK * EMB;     // 3,145,728
    const size_t WSZ = (size_t)EMB * EMB;      //   589,824
    __hip_bfloat16* xb  = (__hip_bfloat16*)d_ws;
    __hip_bfloat16* wqb = xb  + TOK;
    __hip_bfloat16* wkb = wqb + WSZ;
    __hip_bfloat16* wvb = wkb + WSZ;
    __hip_bfloat16* wob = wvb + WSZ;
    __hip_bfloat16* qb  = wob + WSZ;
    __hip_bfloat16* kb  = qb  + TOK;
    __hip_bfloat16* vb  = kb  + TOK;
    __hip_bfloat16* vTb = vb  + TOK;
    __hip_bfloat16* aob = vTb + TOK;           // total ~42.5 MB

    // 0: cast (5,505,024 elems / 8 per thread)
    cast_kernel<<<2688, 256, 0, stream>>>(x, wq, wk, wv, wo, xb, wqb, wkb, wvb, wob);
    // 1: QKV projection  (N=2304 -> 18 col tiles, M=4096 -> 32 row tiles)
    qkv_mfma_kernel<<<dim3(18, 32), 256, 0, stream>>>(xb, wqb, bq, wkb, bk, wvb, bv,
                                                      qb, kb, vb);
    // 2: V transpose per (b,h)
    transpose_v_kernel<<<dim3(32, 24), 256, 0, stream>>>(vb, vTb);
    // 3: attention (768 blocks, heavy-first)
    attn_mfma_kernel<<<768, 256, 0, stream>>>(qb, kb, vTb, aob);
    // 4: output projection
    out_proj_mfma_kernel<<<dim3(6, 32), 256, 0, stream>>>(aob, wob, bo, out);
}

// Round 3
// 186.210 us; speedup vs baseline: 7.0349x; 1.1724x over previous
//
#include <hip/hip_runtime.h>
#include <hip/hip_bf16.h>
#include <math.h>

#define EMB  768
#define NH   12
#define HD   64
#define SEQ  2048
#define BATCH 2
#define NTOK 4096           // BATCH*SEQ

typedef __attribute__((ext_vector_type(8))) short short8;   // 8 bf16 = 4 VGPRs
typedef __attribute__((ext_vector_type(4))) float float4v;  // 4 fp32 acc

static __device__ __forceinline__ short f2bf(float f) {
    __hip_bfloat16 h = __float2bfloat16(f);
    return *reinterpret_cast<short*>(&h);
}

// async global->LDS, 16B per lane.  LDS dest = wave-uniform base + lane*16.
static __device__ __forceinline__ void gll16(const void* g, void* l) {
    __builtin_amdgcn_global_load_lds(
        (const __attribute__((address_space(1))) void*)g,
        (__attribute__((address_space(3))) void*)l, 16, 0, 0);
}

// ---------------------------------------------------------------------------
// Kernel 0: cast x + 4 weights fp32 -> bf16 into workspace.
// ---------------------------------------------------------------------------
__global__ __launch_bounds__(256) void cast_kernel(
    const float* __restrict__ x,  const float* __restrict__ wq,
    const float* __restrict__ wk, const float* __restrict__ wv,
    const float* __restrict__ wo,
    __hip_bfloat16* __restrict__ xb,  __hip_bfloat16* __restrict__ wqb,
    __hip_bfloat16* __restrict__ wkb, __hip_bfloat16* __restrict__ wvb,
    __hip_bfloat16* __restrict__ wob)
{
    const size_t S0 = (size_t)NTOK * EMB;       // 3,145,728
    const size_t S1 = (size_t)EMB * EMB;        //   589,824
    size_t i = ((size_t)blockIdx.x * 256 + threadIdx.x) * 8;
    const float* src; __hip_bfloat16* dst; size_t off;
    if      (i < S0)            { src = x;  dst = xb;  off = i; }
    else if (i < S0 + S1)       { src = wq; dst = wqb; off = i - S0; }
    else if (i < S0 + 2 * S1)   { src = wk; dst = wkb; off = i - S0 - S1; }
    else if (i < S0 + 3 * S1)   { src = wv; dst = wvb; off = i - S0 - 2 * S1; }
    else                        { src = wo; dst = wob; off = i - S0 - 3 * S1; }
    float4 f0 = *(const float4*)&src[off];
    float4 f1 = *(const float4*)&src[off + 4];
    short8 o;
    o[0] = f2bf(f0.x); o[1] = f2bf(f0.y); o[2] = f2bf(f0.z); o[3] = f2bf(f0.w);
    o[4] = f2bf(f1.x); o[5] = f2bf(f1.y); o[6] = f2bf(f1.z); o[7] = f2bf(f1.w);
    *(short8*)&dst[off] = o;
}

// ---------------------------------------------------------------------------
// Kernel 1: fused QKV projection, bf16 MFMA, global_load_lds staging with
// XOR-swizzled LDS (chunk c8' holds global chunk c8 = c8'^(row&7)).
// 128x128 tile, 4 waves each 64x64.  V written directly transposed
// ([bh][d][n]) so no separate transpose kernel.
// ---------------------------------------------------------------------------
__global__ __launch_bounds__(256) void qkv_mfma_kernel(
    const __hip_bfloat16* __restrict__ xb,
    const __hip_bfloat16* __restrict__ wqb, const float* __restrict__ bq,
    const __hip_bfloat16* __restrict__ wkb, const float* __restrict__ bk,
    const __hip_bfloat16* __restrict__ wvb, const float* __restrict__ bv,
    __hip_bfloat16* __restrict__ q, __hip_bfloat16* __restrict__ k,
    __hip_bfloat16* __restrict__ vT)
{
    __shared__ __align__(16) short As[128 * 64];
    __shared__ __align__(16) short Bs[128 * 64];
    const int t = threadIdx.x;
    const int w = t >> 6, lane = t & 63;
    const int col = lane & 15, quad = lane >> 4;
    const int wm = w >> 1, wn = w & 1;
    const int m0 = blockIdx.y * 128;
    const int mat = blockIdx.x / 6;             // 0=q 1=k 2=v
    const int jj0 = (blockIdx.x % 6) * 128;
    const short* X = (const short*)xb;
    const short* W = (const short*)((mat == 0) ? wqb : (mat == 1) ? wkb : wvb);
    const float* bias = (mat == 0) ? bq : (mat == 1) ? bk : bv;

    float4v acc[4][4];
    #pragma unroll
    for (int mi = 0; mi < 4; ++mi)
        #pragma unroll
        for (int ni = 0; ni < 4; ++ni) acc[mi][ni] = (float4v){0.f, 0.f, 0.f, 0.f};

    for (int kb = 0; kb < EMB; kb += 64) {
        #pragma unroll
        for (int c = 0; c < 4; ++c) {
            int I = w * 256 + c * 64 + lane;      // 16B chunk index, 0..1023
            int row = I >> 3;
            int c8 = (I & 7) ^ (row & 7);
            gll16(X + (size_t)(m0 + row) * EMB + kb + c8 * 8,
                  &As[(w * 256 + c * 64) * 8]);
            gll16(W + (size_t)(jj0 + row) * EMB + kb + c8 * 8,
                  &Bs[(w * 256 + c * 64) * 8]);
        }
        __syncthreads();
        #pragma unroll
        for (int ks = 0; ks < 2; ++ks) {
            short8 a[4], b[4];
            #pragma unroll
            for (int mi = 0; mi < 4; ++mi) {
                int row = wm * 64 + mi * 16 + col;
                a[mi] = *(short8*)&As[row * 64 + (((ks * 4 + quad) ^ (row & 7)) * 8)];
            }
            #pragma unroll
            for (int ni = 0; ni < 4; ++ni) {
                int row = wn * 64 + ni * 16 + col;
                b[ni] = *(short8*)&Bs[row * 64 + (((ks * 4 + quad) ^ (row & 7)) * 8)];
            }
            #pragma unroll
            for (int mi = 0; mi < 4; ++mi)
                #pragma unroll
                for (int ni = 0; ni < 4; ++ni)
                    acc[mi][ni] = __builtin_amdgcn_mfma_f32_16x16x32_bf16(
                        a[mi], b[ni], acc[mi][ni], 0, 0, 0);
        }
        __syncthreads();
    }
    const float scale = (mat == 0) ? 0.125f : 1.0f;
    __hip_bfloat16* dstqk = (mat == 0) ? q : k;
    #pragma unroll
    for (int mi = 0; mi < 4; ++mi) {
        #pragma unroll
        for (int ni = 0; ni < 4; ++ni) {
            int gj = jj0 + wn * 64 + ni * 16 + col;   // 0..767
            int h = gj >> 6, d = gj & 63;
            float bsv = bias[gj];
            #pragma unroll
            for (int r = 0; r < 4; ++r) {
                int gm = m0 + wm * 64 + mi * 16 + quad * 4 + r;
                int bi = gm >> 11, n = gm & (SEQ - 1);
                float val = (acc[mi][ni][r] + bsv) * scale;
                if (mat == 2)
                    vT[(((size_t)bi * NH + h) * HD + d) * SEQ + n] = __float2bfloat16(val);
                else
                    dstqk[(((size_t)bi * NH + h) * SEQ + n) * HD + d] = __float2bfloat16(val);
            }
        }
    }
}

// ---------------------------------------------------------------------------
// Kernel 2: flash causal attention, static-max softmax (no running max: scores
// bounded ~|10|, exp(s) safe in fp32).  2 waves x 32 Q rows per 64-row block;
// double-buffered K/V staging via global_load_lds overlapping compute.
// ---------------------------------------------------------------------------
__global__ __launch_bounds__(128) void attn_mfma_kernel(
    const __hip_bfloat16* __restrict__ qg, const __hip_bfloat16* __restrict__ kg,
    const __hip_bfloat16* __restrict__ vTg, __hip_bfloat16* __restrict__ ao)
{
    __shared__ __align__(16) short Ks[2][64 * 64];
    __shared__ __align__(16) short Vt[2][64 * 64];
    __shared__ __align__(16) short Ps[2][32][72];
    const int t = threadIdx.x;
    const int w = t >> 6, lane = t & 63;
    const int col = lane & 15, quad = lane >> 4;
    const int idx = blockIdx.x;
    const int qt = 31 - idx / 24;              // heavy-first
    const int bh = idx % 24;
    const int q0 = qt * 64;
    const size_t base = (size_t)bh * SEQ * HD;
    const short* kp = (const short*)kg + base;
    const short* vp = (const short*)vTg + base;   // [d][n] per bh
    const short* qp = (const short*)qg + base;

    // Q fragments: wave w owns rows q0 + w*32 .. +31 (2 m-tiles)
    short8 qa[2][2];
    #pragma unroll
    for (int mi = 0; mi < 2; ++mi) {
        int qrow = q0 + w * 32 + mi * 16 + col;
        #pragma unroll
        for (int ks = 0; ks < 2; ++ks)
            qa[mi][ks] = *(const short8*)&qp[(size_t)qrow * HD + ks * 32 + quad * 8];
    }
    float4v accO[2][4];
    float lacc[2][4];
    #pragma unroll
    for (int mi = 0; mi < 2; ++mi) {
        #pragma unroll
        for (int di = 0; di < 4; ++di) accO[mi][di] = (float4v){0.f, 0.f, 0.f, 0.f};
        #pragma unroll
        for (int r = 0; r < 4; ++r) lacc[mi][r] = 0.f;
    }

    // prologue: stage tile 0 into buffer 0 (512 chunks per array, 4/lane)
    #pragma unroll
    for (int c = 0; c < 4; ++c) {
        int I = w * 256 + c * 64 + lane;
        int row = I >> 3;
        int c8 = (I & 7) ^ (row & 7);
        gll16(kp + (size_t)row * HD + c8 * 8, &Ks[0][(w * 256 + c * 64) * 8]);
        gll16(vp + (size_t)row * SEQ + c8 * 8, &Vt[0][(w * 256 + c * 64) * 8]);
    }

    for (int kt = 0; kt <= qt; ++kt) {
        const int cur = kt & 1;
        const int k0 = kt * 64;
        __syncthreads();                       // drains staging of tile kt
        if (kt < qt) {                         // prefetch kt+1 into other buffer
            const int kn = k0 + 64;
            #pragma unroll
            for (int c = 0; c < 4; ++c) {
                int I = w * 256 + c * 64 + lane;
                int row = I >> 3;
                int c8 = (I & 7) ^ (row & 7);
                gll16(kp + (size_t)(kn + row) * HD + c8 * 8,
                      &Ks[cur ^ 1][(w * 256 + c * 64) * 8]);
                gll16(vp + (size_t)row * SEQ + kn + c8 * 8,
                      &Vt[cur ^ 1][(w * 256 + c * 64) * 8]);
            }
        }
        const short* Kc = &Ks[cur][0];
        const short* Vc = &Vt[cur][0];

        // S = Q @ K^T
        float4v s[2][4];
        #pragma unroll
        for (int mi = 0; mi < 2; ++mi)
            #pragma unroll
            for (int ni = 0; ni < 4; ++ni) s[mi][ni] = (float4v){0.f, 0.f, 0.f, 0.f};
        #pragma unroll
        for (int ks = 0; ks < 2; ++ks)
            #pragma unroll
            for (int ni = 0; ni < 4; ++ni) {
                int row = ni * 16 + col;
                short8 kf = *(short8*)&Kc[row * 64 + (((ks * 4 + quad) ^ (row & 7)) * 8)];
                #pragma unroll
                for (int mi = 0; mi < 2; ++mi)
                    s[mi][ni] = __builtin_amdgcn_mfma_f32_16x16x32_bf16(
                        qa[mi][ks], kf, s[mi][ni], 0, 0, 0);
            }

        // p = exp(s)  (static max; masked entries -> 0 on diagonal tile)
        if (kt == qt) {
            #pragma unroll
            for (int mi = 0; mi < 2; ++mi)
                #pragma unroll
                for (int ni = 0; ni < 4; ++ni) {
                    int gcol = k0 + ni * 16 + col;
                    #pragma unroll
                    for (int r = 0; r < 4; ++r) {
                        int grow = q0 + w * 32 + mi * 16 + quad * 4 + r;
                        s[mi][ni][r] = (gcol > grow) ? 0.f : __expf(s[mi][ni][r]);
                    }
                }
        } else {
            #pragma unroll
            for (int mi = 0; mi < 2; ++mi)
                #pragma unroll
                for (int ni = 0; ni < 4; ++ni)
                    #pragma unroll
                    for (int r = 0; r < 4; ++r)
                        s[mi][ni][r] = __expf(s[mi][ni][r]);
        }
        #pragma unroll
        for (int mi = 0; mi < 2; ++mi)
            #pragma unroll
            for (int r = 0; r < 4; ++r)
                lacc[mi][r] += (s[mi][0][r] + s[mi][1][r]) + (s[mi][2][r] + s[mi][3][r]);

        // P (C-layout) -> per-wave LDS -> A-layout frags (same-wave, no barrier)
        #pragma unroll
        for (int mi = 0; mi < 2; ++mi)
            #pragma unroll
            for (int ni = 0; ni < 4; ++ni)
                #pragma unroll
                for (int r = 0; r < 4; ++r)
                    Ps[w][mi * 16 + quad * 4 + r][ni * 16 + col] = f2bf(s[mi][ni][r]);
        short8 pa[2][2];
        #pragma unroll
        for (int mi = 0; mi < 2; ++mi)
            #pragma unroll
            for (int ks = 0; ks < 2; ++ks)
                pa[mi][ks] = *(short8*)&Ps[w][mi * 16 + col][ks * 32 + quad * 8];

        // O += P @ V
        #pragma unroll
        for (int ks = 0; ks < 2; ++ks)
            #pragma unroll
            for (int di = 0; di < 4; ++di) {
                int row = di * 16 + col;
                short8 vf = *(short8*)&Vc[row * 64 + (((ks * 4 + quad) ^ (row & 7)) * 8)];
                #pragma unroll
                for (int mi = 0; mi < 2; ++mi)
                    accO[mi][di] = __builtin_amdgcn_mfma_f32_16x16x32_bf16(
                        pa[mi][ks], vf, accO[mi][di], 0, 0, 0);
            }
    }

    // epilogue: row-sum reduce (once), divide, write [b, n, emb] bf16
    #pragma unroll
    for (int msk = 1; msk < 16; msk <<= 1)
        #pragma unroll
        for (int mi = 0; mi < 2; ++mi)
            #pragma unroll
            for (int r = 0; r < 4; ++r)
                lacc[mi][r] += __shfl_xor(lacc[mi][r], msk);
    const int bi = bh / NH, h = bh % NH;
    #pragma unroll
    for (int mi = 0; mi < 2; ++mi)
        #pragma unroll
        for (int r = 0; r < 4; ++r) {
            float inv = 1.0f / lacc[mi][r];
            int n = q0 + w * 32 + mi * 16 + quad * 4 + r;
            #pragma unroll
            for (int di = 0; di < 4; ++di)
                ao[((size_t)bi * SEQ + n) * EMB + h * HD + di * 16 + col] =
                    __float2bfloat16(accO[mi][di][r] * inv);
        }
}

// ---------------------------------------------------------------------------
// Kernel 3: output projection, 64x128 tiles (384 blocks), gll staging.
// ---------------------------------------------------------------------------
__global__ __launch_bounds__(256) void out_proj_mfma_kernel(
    const __hip_bfloat16* __restrict__ a, const __hip_bfloat16* __restrict__ wob,
    const float* __restrict__ bias, float* __restrict__ out)
{
    __shared__ __align__(16) short As[64 * 64];
    __shared__ __align__(16) short Bs[128 * 64];
    const int t = threadIdx.x;
    const int w = t >> 6, lane = t & 63;
    const int col = lane & 15, quad = lane >> 4;
    const int m0 = blockIdx.y * 64;
    const int n0 = blockIdx.x * 128;
    const short* A = (const short*)a;
    const short* W = (const short*)wob;

    float4v acc[4][2];
    #pragma unroll
    for (int mi = 0; mi < 4; ++mi)
        #pragma unroll
        for (int ni = 0; ni < 2; ++ni) acc[mi][ni] = (float4v){0.f, 0.f, 0.f, 0.f};

    for (int kb = 0; kb < EMB; kb += 64) {
        #pragma unroll
        for (int c = 0; c < 2; ++c) {
            int I = w * 128 + c * 64 + lane;     // 0..511
            int row = I >> 3;
            int c8 = (I & 7) ^ (row & 7);
            gll16(A + (size_t)(m0 + row) * EMB + kb + c8 * 8,
                  &As[(w * 128 + c * 64) * 8]);
        }
        #pragma unroll
        for (int c = 0; c < 4; ++c) {
            int I = w * 256 + c * 64 + lane;     // 0..1023
            int row = I >> 3;
            int c8 = (I & 7) ^ (row & 7);
            gll16(W + (size_t)(n0 + row) * EMB + kb + c8 * 8,
                  &Bs[(w * 256 + c * 64) * 8]);
        }
        __syncthreads();
        #pragma unroll
        for (int ks = 0; ks < 2; ++ks) {
            short8 av[4], bv[2];
            #pragma unroll
            for (int mi = 0; mi < 4; ++mi) {
                int row = mi * 16 + col;
                av[mi] = *(short8*)&As[row * 64 + (((ks * 4 + quad) ^ (row & 7)) * 8)];
            }
            #pragma unroll
            for (int ni = 0; ni < 2; ++ni) {
                int row = w * 32 + ni * 16 + col;
                bv[ni] = *(short8*)&Bs[row * 64 + (((ks * 4 + quad) ^ (row & 7)) * 8)];
            }
            #pragma unroll
            for (int mi = 0; mi < 4; ++mi)
                #pragma unroll
                for (int ni = 0; ni < 2; ++ni)
                    acc[mi][ni] = __builtin_amdgcn_mfma_f32_16x16x32_bf16(
                        av[mi], bv[ni], acc[mi][ni], 0, 0, 0);
        }
        __syncthreads();
    }
    #pragma unroll
    for (int mi = 0; mi < 4; ++mi)
        #pragma unroll
        for (int ni = 0; ni < 2; ++ni) {
            int gj = n0 + w * 32 + ni * 16 + col;
            float bsv = bias[gj];
            #pragma unroll
            for (int r = 0; r < 4; ++r) {
                int gm = m0 + mi * 16 + quad * 4 + r;
                out[(size_t)gm * EMB + gj] = acc[mi][ni][r] + bsv;
            }
        }
}

extern "C" void kernel_launch(void* const* d_in, const int* in_sizes, int n_in,
                              void* d_out, int out_size, void* d_ws, size_t ws_size,
                              hipStream_t stream) {
    const float* x  = (const float*)d_in[0];
    const float* wq = (const float*)d_in[1];
    const float* bq = (const float*)d_in[2];
    const float* wk = (const float*)d_in[3];
    const float* bk = (const float*)d_in[4];
    const float* wv = (const float*)d_in[5];
    const float* bv = (const float*)d_in[6];
    const float* wo = (const float*)d_in[7];
    const float* bo = (const float*)d_in[8];
    float* out = (float*)d_out;

    const size_t TOK = (size_t)NTOK * EMB;     // 3,145,728
    const size_t WSZ = (size_t)EMB * EMB;      //   589,824
    __hip_bfloat16* xb  = (__hip_bfloat16*)d_ws;
    __hip_bfloat16* wqb = xb  + TOK;
    __hip_bfloat16* wkb = wqb + WSZ;
    __hip_bfloat16* wvb = wkb + WSZ;
    __hip_bfloat16* wob = wvb + WSZ;
    __hip_bfloat16* qb  = wob + WSZ;
    __hip_bfloat16* kb  = qb  + TOK;
    __hip_bfloat16* vTb = kb  + TOK;
    __hip_bfloat16* aob = vTb + TOK;           // ~36 MB total

    cast_kernel<<<2688, 256, 0, stream>>>(x, wq, wk, wv, wo, xb, wqb, wkb, wvb, wob);
    qkv_mfma_kernel<<<dim3(18, 32), 256, 0, stream>>>(xb, wqb, bq, wkb, bk, wvb, bv,
                                                      qb, kb, vTb);
    attn_mfma_kernel<<<768, 128, 0, stream>>>(qb, kb, vTb, aob);
    out_proj_mfma_kernel<<<dim3(6, 64), 256, 0, stream>>>(aob, wob, bo, out);
}

// Round 4
// 171.961 us; speedup vs baseline: 7.6179x; 1.0829x over previous
//
#include <hip/hip_runtime.h>
#include <hip/hip_bf16.h>
#include <math.h>

#define EMB  768
#define NH   12
#define HD   64
#define SEQ  2048
#define BATCH 2
#define NTOK 4096           // BATCH*SEQ

typedef __attribute__((ext_vector_type(8))) short short8;   // 8 bf16 = 4 VGPRs
typedef __attribute__((ext_vector_type(4))) float float4v;  // 4 fp32 acc

static __device__ __forceinline__ short f2bf(float f) {
    __hip_bfloat16 h = __float2bfloat16(f);
    return *reinterpret_cast<short*>(&h);
}

// async global->LDS, 16B per lane.  LDS dest = wave-uniform base + lane*16.
static __device__ __forceinline__ void gll16(const void* g, void* l) {
    __builtin_amdgcn_global_load_lds(
        (const __attribute__((address_space(1))) void*)g,
        (__attribute__((address_space(3))) void*)l, 16, 0, 0);
}

// ---------------------------------------------------------------------------
// Kernel 0: cast x + 4 weights fp32 -> bf16 into workspace.
// ---------------------------------------------------------------------------
__global__ __launch_bounds__(256) void cast_kernel(
    const float* __restrict__ x,  const float* __restrict__ wq,
    const float* __restrict__ wk, const float* __restrict__ wv,
    const float* __restrict__ wo,
    __hip_bfloat16* __restrict__ xb,  __hip_bfloat16* __restrict__ wqb,
    __hip_bfloat16* __restrict__ wkb, __hip_bfloat16* __restrict__ wvb,
    __hip_bfloat16* __restrict__ wob)
{
    const size_t S0 = (size_t)NTOK * EMB;       // 3,145,728
    const size_t S1 = (size_t)EMB * EMB;        //   589,824
    size_t i = ((size_t)blockIdx.x * 256 + threadIdx.x) * 8;
    const float* src; __hip_bfloat16* dst; size_t off;
    if      (i < S0)            { src = x;  dst = xb;  off = i; }
    else if (i < S0 + S1)       { src = wq; dst = wqb; off = i - S0; }
    else if (i < S0 + 2 * S1)   { src = wk; dst = wkb; off = i - S0 - S1; }
    else if (i < S0 + 3 * S1)   { src = wv; dst = wvb; off = i - S0 - 2 * S1; }
    else                        { src = wo; dst = wob; off = i - S0 - 3 * S1; }
    float4 f0 = *(const float4*)&src[off];
    float4 f1 = *(const float4*)&src[off + 4];
    short8 o;
    o[0] = f2bf(f0.x); o[1] = f2bf(f0.y); o[2] = f2bf(f0.z); o[3] = f2bf(f0.w);
    o[4] = f2bf(f1.x); o[5] = f2bf(f1.y); o[6] = f2bf(f1.z); o[7] = f2bf(f1.w);
    *(short8*)&dst[off] = o;
}

// ---------------------------------------------------------------------------
// Kernel 1: fused QKV projection, bf16 MFMA, gll16 staging, XOR-swizzled LDS.
// V is written transposed ([bh][d][n]) via an LDS transpose for coalescing.
// ---------------------------------------------------------------------------
__global__ __launch_bounds__(256) void qkv_mfma_kernel(
    const __hip_bfloat16* __restrict__ xb,
    const __hip_bfloat16* __restrict__ wqb, const float* __restrict__ bq,
    const __hip_bfloat16* __restrict__ wkb, const float* __restrict__ bk,
    const __hip_bfloat16* __restrict__ wvb, const float* __restrict__ bv,
    __hip_bfloat16* __restrict__ q, __hip_bfloat16* __restrict__ k,
    __hip_bfloat16* __restrict__ vT)
{
    __shared__ __align__(16) short SM[16384];     // As = SM, Bs = SM+8192
    short* As = SM;
    short* Bs = SM + 8192;
    const int t = threadIdx.x;
    const int w = t >> 6, lane = t & 63;
    const int col = lane & 15, quad = lane >> 4;
    const int wm = w >> 1, wn = w & 1;
    const int m0 = blockIdx.y * 128;
    const int mat = blockIdx.x / 6;             // 0=q 1=k 2=v
    const int jj0 = (blockIdx.x % 6) * 128;
    const short* X = (const short*)xb;
    const short* W = (const short*)((mat == 0) ? wqb : (mat == 1) ? wkb : wvb);
    const float* bias = (mat == 0) ? bq : (mat == 1) ? bk : bv;

    float4v acc[4][4];
    #pragma unroll
    for (int mi = 0; mi < 4; ++mi)
        #pragma unroll
        for (int ni = 0; ni < 4; ++ni) acc[mi][ni] = (float4v){0.f, 0.f, 0.f, 0.f};

    for (int kb = 0; kb < EMB; kb += 64) {
        #pragma unroll
        for (int c = 0; c < 4; ++c) {
            int I = w * 256 + c * 64 + lane;      // 16B chunk index, 0..1023
            int row = I >> 3;
            int c8 = (I & 7) ^ (row & 7);
            gll16(X + (size_t)(m0 + row) * EMB + kb + c8 * 8,
                  &As[(w * 256 + c * 64) * 8]);
            gll16(W + (size_t)(jj0 + row) * EMB + kb + c8 * 8,
                  &Bs[(w * 256 + c * 64) * 8]);
        }
        __syncthreads();
        #pragma unroll
        for (int ks = 0; ks < 2; ++ks) {
            short8 a[4], b[4];
            #pragma unroll
            for (int mi = 0; mi < 4; ++mi) {
                int row = wm * 64 + mi * 16 + col;
                a[mi] = *(short8*)&As[row * 64 + (((ks * 4 + quad) ^ (row & 7)) * 8)];
            }
            #pragma unroll
            for (int ni = 0; ni < 4; ++ni) {
                int row = wn * 64 + ni * 16 + col;
                b[ni] = *(short8*)&Bs[row * 64 + (((ks * 4 + quad) ^ (row & 7)) * 8)];
            }
            #pragma unroll
            for (int mi = 0; mi < 4; ++mi)
                #pragma unroll
                for (int ni = 0; ni < 4; ++ni)
                    acc[mi][ni] = __builtin_amdgcn_mfma_f32_16x16x32_bf16(
                        a[mi], b[ni], acc[mi][ni], 0, 0, 0);
        }
        __syncthreads();
    }
    const int bi = m0 >> 11, n0g = m0 & (SEQ - 1);   // tile fits one batch
    if (mat != 2) {
        const float scale = (mat == 0) ? 0.125f : 1.0f;
        __hip_bfloat16* dstqk = (mat == 0) ? q : k;
        #pragma unroll
        for (int mi = 0; mi < 4; ++mi) {
            #pragma unroll
            for (int ni = 0; ni < 4; ++ni) {
                int gj = jj0 + wn * 64 + ni * 16 + col;   // 0..767
                int h = gj >> 6, d = gj & 63;
                float bsv = bias[gj];
                #pragma unroll
                for (int r = 0; r < 4; ++r) {
                    int gm = m0 + wm * 64 + mi * 16 + quad * 4 + r;
                    int bb = gm >> 11, n = gm & (SEQ - 1);
                    dstqk[(((size_t)bb * NH + h) * SEQ + n) * HD + d] =
                        __float2bfloat16((acc[mi][ni][r] + bsv) * scale);
                }
            }
        }
    } else {
        // V: transpose through swizzled LDS (Ts = whole SM, stride 128 shorts)
        #pragma unroll
        for (int mi = 0; mi < 4; ++mi)
            #pragma unroll
            for (int ni = 0; ni < 4; ++ni) {
                int d_l = wn * 64 + ni * 16 + col;        // 0..127 (d_l&15==col)
                float bsv = bias[jj0 + d_l];
                #pragma unroll
                for (int r = 0; r < 4; ++r) {
                    int n_l = wm * 64 + mi * 16 + quad * 4 + r;
                    SM[(d_l << 7) + ((((n_l >> 3) ^ col) << 3) | (n_l & 7))] =
                        f2bf(acc[mi][ni][r] + bsv);
                }
            }
        __syncthreads();
        #pragma unroll
        for (int it = 0; it < 8; ++it) {
            int I = it * 256 + t;                 // 0..2047
            int d_l = I >> 4, c8 = I & 15;
            short8 val = *(short8*)&SM[(d_l << 7) + (c8 << 3)];
            int n_l = (c8 ^ (d_l & 15)) << 3;
            int gj = jj0 + d_l;
            int h = gj >> 6, dd = gj & 63;
            *(short8*)&vT[(((size_t)bi * NH + h) * HD + dd) * SEQ + n0g + n_l] = val;
        }
    }
}

// ---------------------------------------------------------------------------
// Kernel 2: flash causal attention, static-max softmax, KV-split chunks of 16
// tiles.  qt<=15: single chunk, normalized bf16 direct to ao.  qt>=16: two
// chunks write fp32 partials (O_unnorm, l) to deterministic slots 0/1.
// Heavy-first chunk order.  2 waves x 32 q-rows, double-buffered gll16 staging.
// ---------------------------------------------------------------------------
__global__ __launch_bounds__(128) void attn_mfma_kernel(
    const __hip_bfloat16* __restrict__ qg, const __hip_bfloat16* __restrict__ kg,
    const __hip_bfloat16* __restrict__ vTg, __hip_bfloat16* __restrict__ ao,
    float* __restrict__ Os0, float* __restrict__ Os1,
    float* __restrict__ l0, float* __restrict__ l1)
{
    __shared__ __align__(16) short Ks[2][64 * 64];
    __shared__ __align__(16) short Vt[2][64 * 64];
    __shared__ __align__(16) short Ps[2][32][72];
    const int t = threadIdx.x;
    const int w = t >> 6, lane = t & 63;
    const int col = lane & 15, quad = lane >> 4;
    // ---- chunk decode (heavy-first): 48 chunks per bh ----
    const int id = blockIdx.x;
    const int bh = id % 24;
    const int x = id / 24;                     // 0..47
    int qt, c;
    if (x < 16) { qt = 16 + x; c = 0; }        // 16-iter c0 chunks
    else {
        int i = x - 16, j = i >> 1;
        if ((i & 1) == 0) { qt = 31 - j; c = 1; }   // c1: iters qt-15
        else              { qt = 15 - j; c = 0; }   // single: iters qt+1
    }
    const int kt0 = c * 16;
    const int ktend = (kt0 + 16 < qt + 1) ? kt0 + 16 : qt + 1;
    const int niter = ktend - kt0;
    const bool single = (qt <= 15);
    const int q0 = qt * 64;
    const size_t base = (size_t)bh * SEQ * HD;
    const short* kp = (const short*)kg + base;
    const short* vp = (const short*)vTg + base;   // [d][n] per bh
    const short* qp = (const short*)qg + base;

    short8 qa[2][2];
    #pragma unroll
    for (int mi = 0; mi < 2; ++mi) {
        int qrow = q0 + w * 32 + mi * 16 + col;
        #pragma unroll
        for (int ks = 0; ks < 2; ++ks)
            qa[mi][ks] = *(const short8*)&qp[(size_t)qrow * HD + ks * 32 + quad * 8];
    }
    float4v accO[2][4];
    float lacc[2][4];
    #pragma unroll
    for (int mi = 0; mi < 2; ++mi) {
        #pragma unroll
        for (int di = 0; di < 4; ++di) accO[mi][di] = (float4v){0.f, 0.f, 0.f, 0.f};
        #pragma unroll
        for (int r = 0; r < 4; ++r) lacc[mi][r] = 0.f;
    }

    // prologue: stage tile kt0 into buffer 0
    {
        const int k0 = kt0 * 64;
        #pragma unroll
        for (int cc = 0; cc < 4; ++cc) {
            int I = w * 256 + cc * 64 + lane;
            int row = I >> 3;
            int c8 = (I & 7) ^ (row & 7);
            gll16(kp + (size_t)(k0 + row) * HD + c8 * 8, &Ks[0][(w * 256 + cc * 64) * 8]);
            gll16(vp + (size_t)row * SEQ + k0 + c8 * 8, &Vt[0][(w * 256 + cc * 64) * 8]);
        }
    }

    for (int lk = 0; lk < niter; ++lk) {
        const int kt = kt0 + lk;
        const int cur = lk & 1;
        const int k0 = kt * 64;
        __syncthreads();
        if (lk + 1 < niter) {
            const int kn = k0 + 64;
            #pragma unroll
            for (int cc = 0; cc < 4; ++cc) {
                int I = w * 256 + cc * 64 + lane;
                int row = I >> 3;
                int c8 = (I & 7) ^ (row & 7);
                gll16(kp + (size_t)(kn + row) * HD + c8 * 8,
                      &Ks[cur ^ 1][(w * 256 + cc * 64) * 8]);
                gll16(vp + (size_t)row * SEQ + kn + c8 * 8,
                      &Vt[cur ^ 1][(w * 256 + cc * 64) * 8]);
            }
        }
        const short* Kc = &Ks[cur][0];
        const short* Vc = &Vt[cur][0];

        float4v s[2][4];
        #pragma unroll
        for (int mi = 0; mi < 2; ++mi)
            #pragma unroll
            for (int ni = 0; ni < 4; ++ni) s[mi][ni] = (float4v){0.f, 0.f, 0.f, 0.f};
        #pragma unroll
        for (int ks = 0; ks < 2; ++ks)
            #pragma unroll
            for (int ni = 0; ni < 4; ++ni) {
                int row = ni * 16 + col;
                short8 kf = *(short8*)&Kc[row * 64 + (((ks * 4 + quad) ^ (row & 7)) * 8)];
                #pragma unroll
                for (int mi = 0; mi < 2; ++mi)
                    s[mi][ni] = __builtin_amdgcn_mfma_f32_16x16x32_bf16(
                        qa[mi][ks], kf, s[mi][ni], 0, 0, 0);
            }

        if (kt == qt) {
            #pragma unroll
            for (int mi = 0; mi < 2; ++mi)
                #pragma unroll
                for (int ni = 0; ni < 4; ++ni) {
                    int gcol = k0 + ni * 16 + col;
                    #pragma unroll
                    for (int r = 0; r < 4; ++r) {
                        int grow = q0 + w * 32 + mi * 16 + quad * 4 + r;
                        s[mi][ni][r] = (gcol > grow) ? 0.f : __expf(s[mi][ni][r]);
                    }
                }
        } else {
            #pragma unroll
            for (int mi = 0; mi < 2; ++mi)
                #pragma unroll
                for (int ni = 0; ni < 4; ++ni)
                    #pragma unroll
                    for (int r = 0; r < 4; ++r)
                        s[mi][ni][r] = __expf(s[mi][ni][r]);
        }
        #pragma unroll
        for (int mi = 0; mi < 2; ++mi)
            #pragma unroll
            for (int r = 0; r < 4; ++r)
                lacc[mi][r] += (s[mi][0][r] + s[mi][1][r]) + (s[mi][2][r] + s[mi][3][r]);

        #pragma unroll
        for (int mi = 0; mi < 2; ++mi)
            #pragma unroll
            for (int ni = 0; ni < 4; ++ni)
                #pragma unroll
                for (int r = 0; r < 4; ++r)
                    Ps[w][mi * 16 + quad * 4 + r][ni * 16 + col] = f2bf(s[mi][ni][r]);
        short8 pa[2][2];
        #pragma unroll
        for (int mi = 0; mi < 2; ++mi)
            #pragma unroll
            for (int ks = 0; ks < 2; ++ks)
                pa[mi][ks] = *(short8*)&Ps[w][mi * 16 + col][ks * 32 + quad * 8];

        #pragma unroll
        for (int ks = 0; ks < 2; ++ks)
            #pragma unroll
            for (int di = 0; di < 4; ++di) {
                int row = di * 16 + col;
                short8 vf = *(short8*)&Vc[row * 64 + (((ks * 4 + quad) ^ (row & 7)) * 8)];
                #pragma unroll
                for (int mi = 0; mi < 2; ++mi)
                    accO[mi][di] = __builtin_amdgcn_mfma_f32_16x16x32_bf16(
                        pa[mi][ks], vf, accO[mi][di], 0, 0, 0);
            }
    }

    // row-sum reduce across the 16 lanes of each quad-row group
    #pragma unroll
    for (int msk = 1; msk < 16; msk <<= 1)
        #pragma unroll
        for (int mi = 0; mi < 2; ++mi)
            #pragma unroll
            for (int r = 0; r < 4; ++r)
                lacc[mi][r] += __shfl_xor(lacc[mi][r], msk);

    const int bi = bh / NH, h = bh % NH;
    if (single) {
        #pragma unroll
        for (int mi = 0; mi < 2; ++mi)
            #pragma unroll
            for (int r = 0; r < 4; ++r) {
                float inv = 1.0f / lacc[mi][r];
                int n = q0 + w * 32 + mi * 16 + quad * 4 + r;
                #pragma unroll
                for (int di = 0; di < 4; ++di)
                    ao[((size_t)bi * SEQ + n) * EMB + h * HD + di * 16 + col] =
                        __float2bfloat16(accO[mi][di][r] * inv);
            }
    } else {
        float* Os = c ? Os1 : Os0;
        float* ls = c ? l1 : l0;
        #pragma unroll
        for (int mi = 0; mi < 2; ++mi)
            #pragma unroll
            for (int r = 0; r < 4; ++r) {
                int n = q0 + w * 32 + mi * 16 + quad * 4 + r;   // >= 1024
                int nn = n - 1024;
                size_t rowb = ((size_t)bi * 1024 + nn) * EMB + h * HD;
                #pragma unroll
                for (int di = 0; di < 4; ++di)
                    Os[rowb + di * 16 + col] = accO[mi][di][r];
                if (col == 0)
                    ls[((size_t)bi * 1024 + nn) * NH + h] = lacc[mi][r];
            }
    }
}

// ---------------------------------------------------------------------------
// Kernel 3: combine partial slots for tokens n>=1024, normalize, -> ao bf16.
// ---------------------------------------------------------------------------
__global__ __launch_bounds__(256) void combine_kernel(
    const float* __restrict__ Os0, const float* __restrict__ Os1,
    const float* __restrict__ l0, const float* __restrict__ l1,
    __hip_bfloat16* __restrict__ ao)
{
    size_t e8 = ((size_t)blockIdx.x * 256 + threadIdx.x) * 8;  // < 1,572,864
    int u = e8 / EMB;                 // 0..2047 (bi*1024 + nn)
    int within = e8 % EMB;
    int h = within >> 6;
    int bi = u >> 10, nn = u & 1023;
    float inv = 1.0f / (l0[(size_t)u * NH + h] + l1[(size_t)u * NH + h]);
    float4 a0 = *(const float4*)&Os0[e8];
    float4 a1 = *(const float4*)&Os0[e8 + 4];
    float4 b0 = *(const float4*)&Os1[e8];
    float4 b1 = *(const float4*)&Os1[e8 + 4];
    short8 o;
    o[0] = f2bf((a0.x + b0.x) * inv); o[1] = f2bf((a0.y + b0.y) * inv);
    o[2] = f2bf((a0.z + b0.z) * inv); o[3] = f2bf((a0.w + b0.w) * inv);
    o[4] = f2bf((a1.x + b1.x) * inv); o[5] = f2bf((a1.y + b1.y) * inv);
    o[6] = f2bf((a1.z + b1.z) * inv); o[7] = f2bf((a1.w + b1.w) * inv);
    *(short8*)&ao[((size_t)bi * SEQ + 1024 + nn) * EMB + within] = o;
}

// ---------------------------------------------------------------------------
// Kernel 4: output projection, 64x128 tiles (384 blocks), gll staging.
// ---------------------------------------------------------------------------
__global__ __launch_bounds__(256) void out_proj_mfma_kernel(
    const __hip_bfloat16* __restrict__ a, const __hip_bfloat16* __restrict__ wob,
    const float* __restrict__ bias, float* __restrict__ out)
{
    __shared__ __align__(16) short As[64 * 64];
    __shared__ __align__(16) short Bs[128 * 64];
    const int t = threadIdx.x;
    const int w = t >> 6, lane = t & 63;
    const int col = lane & 15, quad = lane >> 4;
    const int m0 = blockIdx.y * 64;
    const int n0 = blockIdx.x * 128;
    const short* A = (const short*)a;
    const short* W = (const short*)wob;

    float4v acc[4][2];
    #pragma unroll
    for (int mi = 0; mi < 4; ++mi)
        #pragma unroll
        for (int ni = 0; ni < 2; ++ni) acc[mi][ni] = (float4v){0.f, 0.f, 0.f, 0.f};

    for (int kb = 0; kb < EMB; kb += 64) {
        #pragma unroll
        for (int c = 0; c < 2; ++c) {
            int I = w * 128 + c * 64 + lane;
            int row = I >> 3;
            int c8 = (I & 7) ^ (row & 7);
            gll16(A + (size_t)(m0 + row) * EMB + kb + c8 * 8,
                  &As[(w * 128 + c * 64) * 8]);
        }
        #pragma unroll
        for (int c = 0; c < 4; ++c) {
            int I = w * 256 + c * 64 + lane;
            int row = I >> 3;
            int c8 = (I & 7) ^ (row & 7);
            gll16(W + (size_t)(n0 + row) * EMB + kb + c8 * 8,
                  &Bs[(w * 256 + c * 64) * 8]);
        }
        __syncthreads();
        #pragma unroll
        for (int ks = 0; ks < 2; ++ks) {
            short8 av[4], bv[2];
            #pragma unroll
            for (int mi = 0; mi < 4; ++mi) {
                int row = mi * 16 + col;
                av[mi] = *(short8*)&As[row * 64 + (((ks * 4 + quad) ^ (row & 7)) * 8)];
            }
            #pragma unroll
            for (int ni = 0; ni < 2; ++ni) {
                int row = w * 32 + ni * 16 + col;
                bv[ni] = *(short8*)&Bs[row * 64 + (((ks * 4 + quad) ^ (row & 7)) * 8)];
            }
            #pragma unroll
            for (int mi = 0; mi < 4; ++mi)
                #pragma unroll
                for (int ni = 0; ni < 2; ++ni)
                    acc[mi][ni] = __builtin_amdgcn_mfma_f32_16x16x32_bf16(
                        av[mi], bv[ni], acc[mi][ni], 0, 0, 0);
        }
        __syncthreads();
    }
    #pragma unroll
    for (int mi = 0; mi < 4; ++mi)
        #pragma unroll
        for (int ni = 0; ni < 2; ++ni) {
            int gj = n0 + w * 32 + ni * 16 + col;
            float bsv = bias[gj];
            #pragma unroll
            for (int r = 0; r < 4; ++r) {
                int gm = m0 + mi * 16 + quad * 4 + r;
                out[(size_t)gm * EMB + gj] = acc[mi][ni][r] + bsv;
            }
        }
}

extern "C" void kernel_launch(void* const* d_in, const int* in_sizes, int n_in,
                              void* d_out, int out_size, void* d_ws, size_t ws_size,
                              hipStream_t stream) {
    const float* x  = (const float*)d_in[0];
    const float* wq = (const float*)d_in[1];
    const float* bq = (const float*)d_in[2];
    const float* wk = (const float*)d_in[3];
    const float* bk = (const float*)d_in[4];
    const float* wv = (const float*)d_in[5];
    const float* bv = (const float*)d_in[6];
    const float* wo = (const float*)d_in[7];
    const float* bo = (const float*)d_in[8];
    float* out = (float*)d_out;

    const size_t TOK = (size_t)NTOK * EMB;     // 3,145,728
    const size_t WSZ = (size_t)EMB * EMB;      //   589,824
    __hip_bfloat16* xb  = (__hip_bfloat16*)d_ws;
    __hip_bfloat16* wqb = xb  + TOK;
    __hip_bfloat16* wkb = wqb + WSZ;
    __hip_bfloat16* wvb = wkb + WSZ;
    __hip_bfloat16* wob = wvb + WSZ;
    __hip_bfloat16* qb  = wob + WSZ;
    __hip_bfloat16* kb  = qb  + TOK;
    __hip_bfloat16* vTb = kb  + TOK;
    __hip_bfloat16* aob = vTb + TOK;
    // fp32 partial slots: Os0 aliases xb (dead after qkv; exact same byte size)
    float* Os0 = (float*)d_ws;                    // 2*1024*768 floats
    float* Os1 = (float*)(aob + TOK);             // fresh
    float* l0  = Os1 + (size_t)2 * 1024 * EMB;    // 2*1024*12 floats
    float* l1  = l0  + (size_t)2 * 1024 * NH;     // total ws ~42.7 MB

    cast_kernel<<<2688, 256, 0, stream>>>(x, wq, wk, wv, wo, xb, wqb, wkb, wvb, wob);
    qkv_mfma_kernel<<<dim3(18, 32), 256, 0, stream>>>(xb, wqb, bq, wkb, bk, wvb, bv,
                                                      qb, kb, vTb);
    attn_mfma_kernel<<<1152, 128, 0, stream>>>(qb, kb, vTb, aob, Os0, Os1, l0, l1);
    combine_kernel<<<768, 256, 0, stream>>>(Os0, Os1, l0, l1, aob);
    out_proj_mfma_kernel<<<dim3(6, 64), 256, 0, stream>>>(aob, wob, bo, out);
}